// Round 8
// baseline (137.971 us; speedup 1.0000x reference)
//
#include <hip/hip_runtime.h>
#include <hip/hip_bf16.h>
#include <stdint.h>

#define N_HEADS 16
#define HEAD_DIM 64
#define SEQ_LEN 2048
#define KVBLK 32
#define QTR_LEN (SEQ_LEN / 4)
#define NTILES (QTR_LEN / KVBLK)   // 16 tiles per quarter-stream

typedef __bf16 bf16x8 __attribute__((ext_vector_type(8)));
typedef __bf16 bf16x4 __attribute__((ext_vector_type(4)));
typedef short  s16x4  __attribute__((ext_vector_type(4)));
typedef float  f32x4  __attribute__((ext_vector_type(4)));
typedef unsigned int u32x4 __attribute__((ext_vector_type(4)));

#if __has_builtin(__builtin_amdgcn_mfma_f32_16x16x16bf16_1k)
#define HAVE_MFMA16 1
#else
#define HAVE_MFMA16 0
#endif

static __device__ __forceinline__ unsigned pkbf(float a, float b) {
    union { __bf16 h[2]; unsigned u; } t;
    t.h[0] = (__bf16)a; t.h[1] = (__bf16)b;
    return t.u;
}

// 16-wave WG (1024 thr), 4-way intra-WG KV split: quarter q (waves 4q..4q+3)
// processes KV[q*512:(q+1)*512) for the same 64 q-rows; wave w4=wave&3 owns
// q-rows qbase..qbase+15. Each quarter has its own double-buffered K/Vt LDS
// stream (addressing identical to verified R7). 4-way flash combine at end.
//
// SWAPPED QK^T: sacc = mfma_16x16x32(A=K-frag, B=Q-frag) = S^T — lane (col,g)
// holds S[q=qbase+col][k=kb+jt*16+g*4+r]. Softmax per-lane scalar + 2+2 shfl.
// ZERO-SHUFFLE PV: two K=16 MFMAs per dt (B = own p[jt][0..3], A = V^T b64 frag).
//   K : row-major bf16 [32][64], addr = row*128 + (off ^ ((row&7)<<4))
//   Vt: transposed bf16, FULL-ADDRESS XOR: addr = (vc*64 + off) ^ ((vc&7)<<4)
// LDS (65536 B): [0,32K) k[qtr][dbuf][4096], [32K,64K) vt[qtr][dbuf][4096].
// Merge overlays [0,50688): eacc 3x16KB + eml 1.5KB.
__global__ __launch_bounds__(1024, 8)
void attn_alibi_kernel(const float* __restrict__ q,
                       const float* __restrict__ k,
                       const float* __restrict__ v,
                       float* __restrict__ out) {
    const int tid  = threadIdx.x;
    const int wave = tid >> 6;
    const int lane = tid & 63;
    const int col  = lane & 15;
    const int g    = lane >> 4;
    const int qtr  = wave >> 2;     // 0..3: KV quarter
    const int w4   = wave & 3;      // q-row group

    const int h      = blockIdx.y;
    const int qbase  = blockIdx.x * 64 + w4 * 16;
    const int kstart = qtr * QTR_LEN;

    const float* qh = q + (size_t)h * SEQ_LEN * HEAD_DIM;
    const float* kh = k + (size_t)h * SEQ_LEN * HEAD_DIM;
    const float* vh = v + (size_t)h * SEQ_LEN * HEAD_DIM;
    float*       oh = out + (size_t)h * SEQ_LEN * HEAD_DIM;

    __shared__ alignas(16) char smem[65536];
    char* kbase  = smem + qtr * 8192;
    char* vtbase = smem + 32768 + qtr * 8192;

    const float LOG2E  = 1.4426950408889634f;
    const float scale2 = 0.125f * LOG2E;
    const float slope  = exp2f(-0.5f * (float)(h + 1));
    const float slope2 = slope * LOG2E;

    // ---- Q B-fragments: lane holds Q[qbase+col][c*32 + g*8 + b] ----
    bf16x8 qf[2];
    {
        const float* qr = qh + (size_t)(qbase + col) * HEAD_DIM + g * 8;
        #pragma unroll
        for (int c = 0; c < 2; ++c)
            #pragma unroll
            for (int b = 0; b < 8; ++b) qf[c][b] = (__bf16)qr[c * 32 + b];
    }

    // ALiBi: cb = slope2*((jt*16+g*4+r) - (qbase+col))
    float cb[2][4];
    #pragma unroll
    for (int jt = 0; jt < 2; ++jt)
        #pragma unroll
        for (int r = 0; r < 4; ++r)
            cb[jt][r] = slope2 * (float)(jt * 16 + g * 4 + r - (qbase + col));

    float m = -1e30f, l = 0.0f;
    f32x4 acc[4];
    #pragma unroll
    for (int dt = 0; dt < 4; ++dt) acc[dt] = (f32x4)0.0f;

    // ---- staging: quarter q's 256 threads stage stream q ----
    const int hid  = tid & 255;
    const int krow = hid >> 3;
    const int kcol = (hid & 7) * 8;
    const float* ksrc = kh + (size_t)(kstart + krow) * HEAD_DIM + kcol;
    char* kdst = kbase + krow * 128 + ((kcol * 2) ^ ((krow & 7) << 4));

    const int vc = hid & 63;
    const int vr = (hid >> 6) * 8;
    const float* vsrc = vh + (size_t)(kstart + vr) * HEAD_DIM + vc;
    char* vtdst = vtbase + (((vc * 64) + (vr * 2)) ^ ((vc & 7) << 4));

    f32x4 kr0, kr1;
    float vv[8];

    // ---- prologue: stage tile 0 ----
    kr0 = *(const f32x4*)(ksrc);
    kr1 = *(const f32x4*)(ksrc + 4);
    #pragma unroll
    for (int j = 0; j < 8; ++j) vv[j] = vsrc[(size_t)j * HEAD_DIM];
    {
        bf16x8 kb16, vb16;
        #pragma unroll
        for (int b = 0; b < 4; ++b) { kb16[b] = (__bf16)kr0[b]; kb16[4 + b] = (__bf16)kr1[b]; }
        #pragma unroll
        for (int j = 0; j < 8; ++j) vb16[j] = (__bf16)vv[j];
        *(bf16x8*)(kdst)  = kb16;
        *(bf16x8*)(vtdst) = vb16;
    }
    __syncthreads();

    for (int t = 0; t < NTILES; ++t) {
        const int kb  = kstart + t * KVBLK;
        const int buf = t & 1;
        const char* kbuf  = kbase + buf * 4096;
        const char* vtbuf = vtbase + buf * 4096;

        // ---- S^T = K Q^T (swapped operands) ----
        f32x4 sacc[2];
        sacc[0] = (f32x4)0.0f;
        sacc[1] = (f32x4)0.0f;
        #pragma unroll
        for (int jt = 0; jt < 2; ++jt) {
            const int row = jt * 16 + col;
            #pragma unroll
            for (int c = 0; c < 2; ++c) {
                bf16x8 kf = *(const bf16x8*)(kbuf + row * 128
                                             + ((c * 64 + g * 16) ^ ((row & 7) << 4)));
                sacc[jt] = __builtin_amdgcn_mfma_f32_16x16x32_bf16(kf, qf[c], sacc[jt], 0, 0, 0);
            }
        }

        // ---- issue next-tile staging loads ----
        if (t + 1 < NTILES) {
            const float* ks = ksrc + (size_t)(t + 1) * KVBLK * HEAD_DIM;
            const float* vs = vsrc + (size_t)(t + 1) * KVBLK * HEAD_DIM;
            kr0 = *(const f32x4*)(ks);
            kr1 = *(const f32x4*)(ks + 4);
            #pragma unroll
            for (int j = 0; j < 8; ++j) vv[j] = vs[(size_t)j * HEAD_DIM];
        }

        // ---- scale + alibi (base-2); lane holds s[k-local] for its q-row ----
        const float skb = slope2 * (float)kb;
        float s[2][4];
        #pragma unroll
        for (int jt = 0; jt < 2; ++jt)
            #pragma unroll
            for (int r = 0; r < 4; ++r)
                s[jt][r] = sacc[jt][r] * scale2 + (cb[jt][r] + skb);

        // ---- online softmax: scalar per lane, 2+2 shfl across g-groups ----
        float x = s[0][0];
        #pragma unroll
        for (int jt = 0; jt < 2; ++jt)
            #pragma unroll
            for (int r = 0; r < 4; ++r) x = fmaxf(x, s[jt][r]);
        x = fmaxf(x, __shfl_xor(x, 16));
        x = fmaxf(x, __shfl_xor(x, 32));
        float mn    = fmaxf(m, x);
        float alpha = __builtin_amdgcn_exp2f(m - mn);
        m = mn;
        float p[2][4], y = 0.0f;
        #pragma unroll
        for (int jt = 0; jt < 2; ++jt)
            #pragma unroll
            for (int r = 0; r < 4; ++r) {
                p[jt][r] = __builtin_amdgcn_exp2f(s[jt][r] - mn);
                y += p[jt][r];
            }
        y += __shfl_xor(y, 16);
        y += __shfl_xor(y, 32);
        l = l * alpha + y;
        #pragma unroll
        for (int dt = 0; dt < 4; ++dt) acc[dt] *= alpha;

#if HAVE_MFMA16
        // ---- ZERO-SHUFFLE PV: two K=16 MFMAs per dt; B = own p[jt][*] ----
        bf16x4 pf0, pf1;
        #pragma unroll
        for (int b = 0; b < 4; ++b) { pf0[b] = (__bf16)p[0][b]; pf1[b] = (__bf16)p[1][b]; }
        const s16x4 pb0 = __builtin_bit_cast(s16x4, pf0);
        const s16x4 pb1 = __builtin_bit_cast(s16x4, pf1);
        #pragma unroll
        for (int dt = 0; dt < 4; ++dt) {
            const int vrow = dt * 16 + col;
            const int rb   = vrow * 64;
            const int swz  = (vrow & 7) << 4;
            bf16x4 vf0 = *(const bf16x4*)(vtbuf + ((rb + g * 8) ^ swz));
            bf16x4 vf1 = *(const bf16x4*)(vtbuf + ((rb + 32 + g * 8) ^ swz));
            acc[dt] = __builtin_amdgcn_mfma_f32_16x16x16bf16_1k(
                __builtin_bit_cast(s16x4, vf0), pb0, acc[dt], 0, 0, 0);
            acc[dt] = __builtin_amdgcn_mfma_f32_16x16x16bf16_1k(
                __builtin_bit_cast(s16x4, vf1), pb1, acc[dt], 0, 0, 0);
        }
#else
        // ---- fallback: pack + 8-shfl permute + K=32 PV ----
        unsigned pk00 = pkbf(p[0][0], p[0][1]);
        unsigned pk01 = pkbf(p[0][2], p[0][3]);
        unsigned pk10 = pkbf(p[1][0], p[1][1]);
        unsigned pk11 = pkbf(p[1][2], p[1][3]);
        const int srcA = col + ((g & 1) << 5);
        const int srcB = srcA + 16;
        unsigned a00 = __shfl(pk00, srcA), a01 = __shfl(pk01, srcA);
        unsigned a10 = __shfl(pk10, srcA), a11 = __shfl(pk11, srcA);
        unsigned b00 = __shfl(pk00, srcB), b01 = __shfl(pk01, srcB);
        unsigned b10 = __shfl(pk10, srcB), b11 = __shfl(pk11, srcB);
        const bool hi = g >= 2;
        u32x4 pu;
        pu[0] = hi ? a10 : a00;
        pu[1] = hi ? a11 : a01;
        pu[2] = hi ? b10 : b00;
        pu[3] = hi ? b11 : b01;
        bf16x8 pf = __builtin_bit_cast(bf16x8, pu);
        #pragma unroll
        for (int dt = 0; dt < 4; ++dt) {
            const int vrow = dt * 16 + col;
            bf16x8 vf = *(const bf16x8*)(vtbuf
                            + ((vrow * 64 + g * 16) ^ ((vrow & 7) << 4)));
            acc[dt] = __builtin_amdgcn_mfma_f32_16x16x32_bf16(vf, pf, acc[dt], 0, 0, 0);
        }
#endif

        // ---- write next tile into the other LDS buffer ----
        if (t + 1 < NTILES) {
            bf16x8 kb16, vb16;
            #pragma unroll
            for (int b = 0; b < 4; ++b) { kb16[b] = (__bf16)kr0[b]; kb16[4 + b] = (__bf16)kr1[b]; }
            #pragma unroll
            for (int j = 0; j < 8; ++j) vb16[j] = (__bf16)vv[j];
            *(bf16x8*)(kdst  + ((t + 1) & 1) * 4096) = kb16;
            *(bf16x8*)(vtdst + ((t + 1) & 1) * 4096) = vb16;
        }
        __syncthreads();
    }

    // ---- 4-way merge (flash combine in O^T layout, base-2 domain) ----
    // overlay: eacc[qtr-1][w4][16 q][64 d] f32 (3x16KB), eml at +49152
    float* eacc = (float*)smem;
    float* eml  = (float*)(smem + 49152);   // [(qtr-1)*64 + w4*16 + col]*2

    if (qtr != 0) {
        float* ea = eacc + (qtr - 1) * 4096 + w4 * 1024 + col * 64;
        #pragma unroll
        for (int dt = 0; dt < 4; ++dt)
            *(f32x4*)(ea + dt * 16 + g * 4) = acc[dt];
        if (g == 0) {
            eml[((qtr - 1) * 64 + w4 * 16 + col) * 2 + 0] = m;
            eml[((qtr - 1) * 64 + w4 * 16 + col) * 2 + 1] = l;
        }
    }
    __syncthreads();
    if (qtr == 0) {
        float mi[3], li[3];
        float mm = m;
        #pragma unroll
        for (int i = 0; i < 3; ++i) {
            mi[i] = eml[(i * 64 + w4 * 16 + col) * 2 + 0];
            li[i] = eml[(i * 64 + w4 * 16 + col) * 2 + 1];
            mm = fmaxf(mm, mi[i]);
        }
        float a0 = __builtin_amdgcn_exp2f(m - mm);
        float lt = l * a0;
        float ai[3];
        #pragma unroll
        for (int i = 0; i < 3; ++i) {
            ai[i] = __builtin_amdgcn_exp2f(mi[i] - mm);
            lt += li[i] * ai[i];
        }
        float inv = 1.0f / lt;
        float* orow = oh + (size_t)(qbase + col) * HEAD_DIM;
        #pragma unroll
        for (int dt = 0; dt < 4; ++dt) {
            f32x4 o = acc[dt] * a0;
            #pragma unroll
            for (int i = 0; i < 3; ++i)
                o += *(const f32x4*)(eacc + i * 4096 + w4 * 1024 + col * 64 + dt * 16 + g * 4) * ai[i];
            *(f32x4*)(orow + dt * 16 + g * 4) = o * inv;
        }
    }
}

extern "C" void kernel_launch(void* const* d_in, const int* in_sizes, int n_in,
                              void* d_out, int out_size, void* d_ws, size_t ws_size,
                              hipStream_t stream) {
    const float* q = (const float*)d_in[0];
    const float* k = (const float*)d_in[1];
    const float* v = (const float*)d_in[2];
    float* out = (float*)d_out;

    dim3 grid(SEQ_LEN / 64, N_HEADS, 1);
    dim3 block(1024, 1, 1);
    attn_alibi_kernel<<<grid, block, 0, stream>>>(q, k, v, out);
}

// Round 9
// 59.383 us; speedup vs baseline: 2.3234x; 2.3234x over previous
//
#include <hip/hip_runtime.h>
#include <hip/hip_bf16.h>
#include <stdint.h>

#define N_HEADS 16
#define HEAD_DIM 64
#define SEQ_LEN 2048
#define KVBLK 32

typedef __bf16 bf16x8 __attribute__((ext_vector_type(8)));
typedef __bf16 bf16x4 __attribute__((ext_vector_type(4)));
typedef short  s16x4  __attribute__((ext_vector_type(4)));
typedef float  f32x4  __attribute__((ext_vector_type(4)));
typedef unsigned int u32x4 __attribute__((ext_vector_type(4)));

#if __has_builtin(__builtin_amdgcn_mfma_f32_16x16x16bf16_1k)
#define HAVE_MFMA16 1
#else
#define HAVE_MFMA16 0
#endif

static __device__ __forceinline__ unsigned pkbf(float a, float b) {
    union { __bf16 h[2]; unsigned u; } t;
    t.h[0] = (__bf16)a; t.h[1] = (__bf16)b;
    return t.u;
}

// R7-verified body (512 thr, 8 waves, internal 2-way KV split, 56 VGPR), now
// templated: NT = tiles per stream; PARTIAL = write unnormalized (m,l,O^T)
// partials to workspace (grid.z KV split) instead of final output.
// R8 lesson: do NOT force occupancy via __launch_bounds__ mins (spills);
// add parallelism at the GRID level and let 56 VGPR earn 8 waves/SIMD.
//   K : row-major bf16 [32][64], addr = row*128 + (off ^ ((row&7)<<4))
//   Vt: transposed bf16, FULL-ADDRESS XOR: addr = (vc*64 + off) ^ ((vc&7)<<4)
// LDS (32768 B): [0,16K) k[half][dbuf][4096] (merge overlays), [16K,32K) vt.
template <int NT, bool PARTIAL>
__global__ __launch_bounds__(512, 4)
void attn_alibi_kernel(const float* __restrict__ q,
                       const float* __restrict__ k,
                       const float* __restrict__ v,
                       float* __restrict__ out,
                       float* __restrict__ wsO,
                       float* __restrict__ wsML) {
    const int tid  = threadIdx.x;
    const int wave = tid >> 6;
    const int lane = tid & 63;
    const int col  = lane & 15;
    const int g    = lane >> 4;
    const int half = wave >> 2;
    const int w4   = wave & 3;

    const int h      = blockIdx.y;
    const int qbase  = blockIdx.x * 64 + w4 * 16;
    const int kstart = blockIdx.z * (2 * NT * KVBLK) + half * (NT * KVBLK);

    const float* qh = q + (size_t)h * SEQ_LEN * HEAD_DIM;
    const float* kh = k + (size_t)h * SEQ_LEN * HEAD_DIM;
    const float* vh = v + (size_t)h * SEQ_LEN * HEAD_DIM;

    __shared__ alignas(16) char smem[32768];
    char* kbase  = smem + half * 8192;
    char* vtbase = smem + 16384 + half * 8192;

    const float LOG2E  = 1.4426950408889634f;
    const float scale2 = 0.125f * LOG2E;
    const float slope  = exp2f(-0.5f * (float)(h + 1));
    const float slope2 = slope * LOG2E;

    // ---- Q B-fragments: lane holds Q[qbase+col][c*32 + g*8 + b] ----
    bf16x8 qf[2];
    {
        const float* qr = qh + (size_t)(qbase + col) * HEAD_DIM + g * 8;
        #pragma unroll
        for (int c = 0; c < 2; ++c)
            #pragma unroll
            for (int b = 0; b < 8; ++b) qf[c][b] = (__bf16)qr[c * 32 + b];
    }

    // ALiBi: cb = slope2*((jt*16+g*4+r) - (qbase+col))
    float cb[2][4];
    #pragma unroll
    for (int jt = 0; jt < 2; ++jt)
        #pragma unroll
        for (int r = 0; r < 4; ++r)
            cb[jt][r] = slope2 * (float)(jt * 16 + g * 4 + r - (qbase + col));

    float m = -1e30f, l = 0.0f;
    f32x4 acc[4];
    #pragma unroll
    for (int dt = 0; dt < 4; ++dt) acc[dt] = (f32x4)0.0f;

    // ---- staging: each half's 256 threads stage that half's stream ----
    const int hid  = tid & 255;
    const int krow = hid >> 3;
    const int kcol = (hid & 7) * 8;
    const float* ksrc = kh + (size_t)(kstart + krow) * HEAD_DIM + kcol;
    char* kdst = kbase + krow * 128 + ((kcol * 2) ^ ((krow & 7) << 4));

    const int vc = hid & 63;
    const int vr = (hid >> 6) * 8;
    const float* vsrc = vh + (size_t)(kstart + vr) * HEAD_DIM + vc;
    char* vtdst = vtbase + (((vc * 64) + (vr * 2)) ^ ((vc & 7) << 4));

    f32x4 kr0, kr1;
    float vv[8];

    // ---- prologue: stage tile 0 ----
    kr0 = *(const f32x4*)(ksrc);
    kr1 = *(const f32x4*)(ksrc + 4);
    #pragma unroll
    for (int j = 0; j < 8; ++j) vv[j] = vsrc[(size_t)j * HEAD_DIM];
    {
        bf16x8 kb16, vb16;
        #pragma unroll
        for (int b = 0; b < 4; ++b) { kb16[b] = (__bf16)kr0[b]; kb16[4 + b] = (__bf16)kr1[b]; }
        #pragma unroll
        for (int j = 0; j < 8; ++j) vb16[j] = (__bf16)vv[j];
        *(bf16x8*)(kdst)  = kb16;
        *(bf16x8*)(vtdst) = vb16;
    }
    __syncthreads();

    for (int t = 0; t < NT; ++t) {
        const int kb  = kstart + t * KVBLK;
        const int buf = t & 1;
        const char* kbuf  = kbase + buf * 4096;
        const char* vtbuf = vtbase + buf * 4096;

        // ---- S^T = K Q^T (swapped operands) ----
        f32x4 sacc[2];
        sacc[0] = (f32x4)0.0f;
        sacc[1] = (f32x4)0.0f;
        #pragma unroll
        for (int jt = 0; jt < 2; ++jt) {
            const int row = jt * 16 + col;
            #pragma unroll
            for (int c = 0; c < 2; ++c) {
                bf16x8 kf = *(const bf16x8*)(kbuf + row * 128
                                             + ((c * 64 + g * 16) ^ ((row & 7) << 4)));
                sacc[jt] = __builtin_amdgcn_mfma_f32_16x16x32_bf16(kf, qf[c], sacc[jt], 0, 0, 0);
            }
        }

        // ---- issue next-tile staging loads ----
        if (t + 1 < NT) {
            const float* ks = ksrc + (size_t)(t + 1) * KVBLK * HEAD_DIM;
            const float* vs = vsrc + (size_t)(t + 1) * KVBLK * HEAD_DIM;
            kr0 = *(const f32x4*)(ks);
            kr1 = *(const f32x4*)(ks + 4);
            #pragma unroll
            for (int j = 0; j < 8; ++j) vv[j] = vs[(size_t)j * HEAD_DIM];
        }

        // ---- scale + alibi (base-2); lane holds s[k-local] for its q-row ----
        const float skb = slope2 * (float)kb;
        float s[2][4];
        #pragma unroll
        for (int jt = 0; jt < 2; ++jt)
            #pragma unroll
            for (int r = 0; r < 4; ++r)
                s[jt][r] = sacc[jt][r] * scale2 + (cb[jt][r] + skb);

        // ---- online softmax: scalar per lane, 2+2 shfl across g-groups ----
        float x = s[0][0];
        #pragma unroll
        for (int jt = 0; jt < 2; ++jt)
            #pragma unroll
            for (int r = 0; r < 4; ++r) x = fmaxf(x, s[jt][r]);
        x = fmaxf(x, __shfl_xor(x, 16));
        x = fmaxf(x, __shfl_xor(x, 32));
        float mn    = fmaxf(m, x);
        float alpha = __builtin_amdgcn_exp2f(m - mn);
        m = mn;
        float p[2][4], y = 0.0f;
        #pragma unroll
        for (int jt = 0; jt < 2; ++jt)
            #pragma unroll
            for (int r = 0; r < 4; ++r) {
                p[jt][r] = __builtin_amdgcn_exp2f(s[jt][r] - mn);
                y += p[jt][r];
            }
        y += __shfl_xor(y, 16);
        y += __shfl_xor(y, 32);
        l = l * alpha + y;
        #pragma unroll
        for (int dt = 0; dt < 4; ++dt) acc[dt] *= alpha;

#if HAVE_MFMA16
        // ---- ZERO-SHUFFLE PV: two K=16 MFMAs per dt; B = own p[jt][*] ----
        bf16x4 pf0, pf1;
        #pragma unroll
        for (int b = 0; b < 4; ++b) { pf0[b] = (__bf16)p[0][b]; pf1[b] = (__bf16)p[1][b]; }
        const s16x4 pb0 = __builtin_bit_cast(s16x4, pf0);
        const s16x4 pb1 = __builtin_bit_cast(s16x4, pf1);
        #pragma unroll
        for (int dt = 0; dt < 4; ++dt) {
            const int vrow = dt * 16 + col;
            const int rb   = vrow * 64;
            const int swz  = (vrow & 7) << 4;
            bf16x4 vf0 = *(const bf16x4*)(vtbuf + ((rb + g * 8) ^ swz));
            bf16x4 vf1 = *(const bf16x4*)(vtbuf + ((rb + 32 + g * 8) ^ swz));
            acc[dt] = __builtin_amdgcn_mfma_f32_16x16x16bf16_1k(
                __builtin_bit_cast(s16x4, vf0), pb0, acc[dt], 0, 0, 0);
            acc[dt] = __builtin_amdgcn_mfma_f32_16x16x16bf16_1k(
                __builtin_bit_cast(s16x4, vf1), pb1, acc[dt], 0, 0, 0);
        }
#else
        // ---- fallback: pack + 8-shfl permute + K=32 PV ----
        unsigned pk00 = pkbf(p[0][0], p[0][1]);
        unsigned pk01 = pkbf(p[0][2], p[0][3]);
        unsigned pk10 = pkbf(p[1][0], p[1][1]);
        unsigned pk11 = pkbf(p[1][2], p[1][3]);
        const int srcA = col + ((g & 1) << 5);
        const int srcB = srcA + 16;
        unsigned a00 = __shfl(pk00, srcA), a01 = __shfl(pk01, srcA);
        unsigned a10 = __shfl(pk10, srcA), a11 = __shfl(pk11, srcA);
        unsigned b00 = __shfl(pk00, srcB), b01 = __shfl(pk01, srcB);
        unsigned b10 = __shfl(pk10, srcB), b11 = __shfl(pk11, srcB);
        const bool hi = g >= 2;
        u32x4 pu;
        pu[0] = hi ? a10 : a00;
        pu[1] = hi ? a11 : a01;
        pu[2] = hi ? b10 : b00;
        pu[3] = hi ? b11 : b01;
        bf16x8 pf = __builtin_bit_cast(bf16x8, pu);
        #pragma unroll
        for (int dt = 0; dt < 4; ++dt) {
            const int vrow = dt * 16 + col;
            bf16x8 vf = *(const bf16x8*)(vtbuf
                            + ((vrow * 64 + g * 16) ^ ((vrow & 7) << 4)));
            acc[dt] = __builtin_amdgcn_mfma_f32_16x16x32_bf16(vf, pf, acc[dt], 0, 0, 0);
        }
#endif

        // ---- write next tile into the other LDS buffer ----
        if (t + 1 < NT) {
            bf16x8 kb16, vb16;
            #pragma unroll
            for (int b = 0; b < 4; ++b) { kb16[b] = (__bf16)kr0[b]; kb16[4 + b] = (__bf16)kr1[b]; }
            #pragma unroll
            for (int j = 0; j < 8; ++j) vb16[j] = (__bf16)vv[j];
            *(bf16x8*)(kdst  + ((t + 1) & 1) * 4096) = kb16;
            *(bf16x8*)(vtdst + ((t + 1) & 1) * 4096) = vb16;
        }
        __syncthreads();
    }

    // ---- merge halves (flash combine in O^T layout, base-2 domain) ----
    float* eacc = (float*)smem;            // [w4][q=col 16][d 64]
    float* eml  = (float*)(smem + 16384);  // [w4*16+col]*2

    if (half == 1) {
        #pragma unroll
        for (int dt = 0; dt < 4; ++dt)
            *(f32x4*)(eacc + w4 * 1024 + col * 64 + dt * 16 + g * 4) = acc[dt];
        if (g == 0) {
            eml[(w4 * 16 + col) * 2 + 0] = m;
            eml[(w4 * 16 + col) * 2 + 1] = l;
        }
    }
    __syncthreads();
    if (half == 0) {
        float m2 = eml[(w4 * 16 + col) * 2 + 0];
        float l2 = eml[(w4 * 16 + col) * 2 + 1];
        float mm = fmaxf(m, m2);
        float a1 = __builtin_amdgcn_exp2f(m - mm);
        float a2 = __builtin_amdgcn_exp2f(m2 - mm);
        float lt = l * a1 + l2 * a2;

        if (PARTIAL) {
            const size_t zrow = (size_t)blockIdx.z * (N_HEADS * SEQ_LEN)
                              + (size_t)h * SEQ_LEN + qbase + col;
            float* orow = wsO + zrow * HEAD_DIM;
            #pragma unroll
            for (int dt = 0; dt < 4; ++dt) {
                f32x4 o2 = *(const f32x4*)(eacc + w4 * 1024 + col * 64 + dt * 16 + g * 4);
                *(f32x4*)(orow + dt * 16 + g * 4) = acc[dt] * a1 + o2 * a2;
            }
            if (g == 0) {
                wsML[zrow * 2 + 0] = mm;
                wsML[zrow * 2 + 1] = lt;
            }
        } else {
            float inv = 1.0f / lt;
            float* orow = out + ((size_t)h * SEQ_LEN + qbase + col) * HEAD_DIM;
            #pragma unroll
            for (int dt = 0; dt < 4; ++dt) {
                f32x4 o2 = *(const f32x4*)(eacc + w4 * 1024 + col * 64 + dt * 16 + g * 4);
                *(f32x4*)(orow + dt * 16 + g * 4) = (acc[dt] * a1 + o2 * a2) * inv;
            }
        }
    }
}

// Combine the two z-slices: out = (O0*a0 + O1*a1) / (l0*a0 + l1*a1).
__global__ __launch_bounds__(256)
void merge_kernel(const float* __restrict__ wsO,
                  const float* __restrict__ wsML,
                  float* __restrict__ out) {
    const int idx  = blockIdx.x * 256 + threadIdx.x;   // 524288 f32x4 chunks
    const int row  = idx >> 4;                         // h*2048 + q, 32768 rows
    const int quad = idx & 15;
    const int NROW = N_HEADS * SEQ_LEN;

    float m0 = wsML[(size_t)row * 2 + 0];
    float l0 = wsML[(size_t)row * 2 + 1];
    float m1 = wsML[((size_t)NROW + row) * 2 + 0];
    float l1 = wsML[((size_t)NROW + row) * 2 + 1];
    float mm = fmaxf(m0, m1);
    float a0 = __builtin_amdgcn_exp2f(m0 - mm);
    float a1 = __builtin_amdgcn_exp2f(m1 - mm);
    float inv = 1.0f / (l0 * a0 + l1 * a1);

    f32x4 o0 = *(const f32x4*)(wsO + (size_t)row * HEAD_DIM + quad * 4);
    f32x4 o1 = *(const f32x4*)(wsO + ((size_t)NROW + row) * HEAD_DIM + quad * 4);
    *(f32x4*)(out + (size_t)row * HEAD_DIM + quad * 4) = (o0 * a0 + o1 * a1) * inv;
}

extern "C" void kernel_launch(void* const* d_in, const int* in_sizes, int n_in,
                              void* d_out, int out_size, void* d_ws, size_t ws_size,
                              hipStream_t stream) {
    const float* q = (const float*)d_in[0];
    const float* k = (const float*)d_in[1];
    const float* v = (const float*)d_in[2];
    float* out = (float*)d_out;

    const size_t nO  = (size_t)2 * N_HEADS * SEQ_LEN * HEAD_DIM;   // 4 MiF
    const size_t nML = (size_t)2 * N_HEADS * SEQ_LEN * 2;
    const size_t need = (nO + nML) * sizeof(float);                // ~17.3 MB

    if (ws_size >= need) {
        float* wsO  = (float*)d_ws;
        float* wsML = wsO + nO;
        dim3 grid(SEQ_LEN / 64, N_HEADS, 2);
        attn_alibi_kernel<16, true><<<grid, dim3(512, 1, 1), 0, stream>>>(
            q, k, v, out, wsO, wsML);
        merge_kernel<<<dim3(2048, 1, 1), dim3(256, 1, 1), 0, stream>>>(wsO, wsML, out);
    } else {
        dim3 grid(SEQ_LEN / 64, N_HEADS, 1);
        attn_alibi_kernel<32, false><<<grid, dim3(512, 1, 1), 0, stream>>>(
            q, k, v, out, nullptr, nullptr);
    }
}

// Round 10
// 51.426 us; speedup vs baseline: 2.6829x; 1.1547x over previous
//
#include <hip/hip_runtime.h>
#include <hip/hip_bf16.h>
#include <stdint.h>

#define N_HEADS 16
#define HEAD_DIM 64
#define SEQ_LEN 2048
#define KVBLK 32
#define NT 32                      // tiles per half-stream (2 halves per WG)
#define NTILE_TOT (SEQ_LEN / KVBLK)

typedef __bf16 bf16x8 __attribute__((ext_vector_type(8)));
typedef __bf16 bf16x4 __attribute__((ext_vector_type(4)));
typedef short  s16x4  __attribute__((ext_vector_type(4)));
typedef float  f32x4  __attribute__((ext_vector_type(4)));
typedef unsigned int u32x4 __attribute__((ext_vector_type(4)));

#if __has_builtin(__builtin_amdgcn_mfma_f32_16x16x16bf16_1k)
#define HAVE_MFMA16 1
#else
#define HAVE_MFMA16 0
#endif

static __device__ __forceinline__ unsigned pkbf(float a, float b) {
    union { __bf16 h[2]; unsigned u; } t;
    t.h[0] = (__bf16)a; t.h[1] = (__bf16)b;
    return t.u;
}

// Prep: build swizzled bf16 images of K (row-major) and Vt (transposed), one
// 4 KB block per (head, 32-row tile) — byte-exact replicas of the verified R7
// LDS tiles (IDENTICAL write formulas, executed once instead of 32x/head).
//   K : row-major bf16 [32][64], addr = row*128 + (off ^ ((row&7)<<4))
//   Vt: transposed bf16, FULL-ADDRESS XOR: addr = (vc*64 + off) ^ ((vc&7)<<4)
__global__ __launch_bounds__(256)
void prep_kernel(const float* __restrict__ k,
                 const float* __restrict__ v,
                 char* __restrict__ kimg,
                 char* __restrict__ vtimg) {
    const int ts  = blockIdx.x;         // tile 0..63
    const int h   = blockIdx.y;
    const int tid = threadIdx.x;
    const int s0  = ts * KVBLK;
    const size_t blk = ((size_t)h * NTILE_TOT + ts) * 4096;

    // K: thread -> K[s0+krow][kcol..kcol+7]
    const int krow = tid >> 3;
    const int kcol = (tid & 7) * 8;
    const float* ks = k + ((size_t)h * SEQ_LEN + s0 + krow) * HEAD_DIM + kcol;
    f32x4 a = *(const f32x4*)ks;
    f32x4 b = *(const f32x4*)(ks + 4);
    bf16x8 kb;
    #pragma unroll
    for (int i = 0; i < 4; ++i) { kb[i] = (__bf16)a[i]; kb[4 + i] = (__bf16)b[i]; }
    *(bf16x8*)(kimg + blk + krow * 128 + ((kcol * 2) ^ ((krow & 7) << 4))) = kb;

    // Vt: thread -> column vc, rows vr..vr+7 (coalesced across lanes per j)
    const int vc = tid & 63;
    const int vr = (tid >> 6) * 8;
    const float* vs = v + ((size_t)h * SEQ_LEN + s0 + vr) * HEAD_DIM + vc;
    bf16x8 vb;
    #pragma unroll
    for (int j = 0; j < 8; ++j) vb[j] = (__bf16)vs[(size_t)j * HEAD_DIM];
    *(bf16x8*)(vtimg + blk + (((vc * 64) + (vr * 2)) ^ ((vc & 7) << 4))) = vb;
}

// R7-verified body. IMG=true: staging is a VERBATIM 16B-per-thread copy of the
// prebuilt image blocks (no cvt, no gather, no swizzle math on the hot path).
// IMG=false: original R7 direct-fp32 staging (fallback).
// R8/R9 lessons: don't force occupancy (spills) and don't add grid parallelism
// (12-wave/CU plateau) — cut per-wave instructions instead.
template <bool IMG>
__global__ __launch_bounds__(512, 4)
void attn_alibi_kernel(const float* __restrict__ q,
                       const float* __restrict__ k,
                       const float* __restrict__ v,
                       float* __restrict__ out,
                       const char* __restrict__ kimg,
                       const char* __restrict__ vtimg) {
    const int tid  = threadIdx.x;
    const int wave = tid >> 6;
    const int lane = tid & 63;
    const int col  = lane & 15;
    const int g    = lane >> 4;
    const int half = wave >> 2;
    const int w4   = wave & 3;

    const int h      = blockIdx.y;
    const int qbase  = blockIdx.x * 64 + w4 * 16;
    const int kstart = half * (NT * KVBLK);

    const float* qh = q + (size_t)h * SEQ_LEN * HEAD_DIM;
    const float* kh = k + (size_t)h * SEQ_LEN * HEAD_DIM;
    const float* vh = v + (size_t)h * SEQ_LEN * HEAD_DIM;

    __shared__ alignas(16) char smem[32768];
    char* kbase  = smem + half * 8192;
    char* vtbase = smem + 16384 + half * 8192;

    const float LOG2E  = 1.4426950408889634f;
    const float scale2 = 0.125f * LOG2E;
    const float slope  = exp2f(-0.5f * (float)(h + 1));
    const float slope2 = slope * LOG2E;

    // ---- Q B-fragments: lane holds Q[qbase+col][c*32 + g*8 + b] ----
    bf16x8 qf[2];
    {
        const float* qr = qh + (size_t)(qbase + col) * HEAD_DIM + g * 8;
        #pragma unroll
        for (int c = 0; c < 2; ++c)
            #pragma unroll
            for (int b = 0; b < 8; ++b) qf[c][b] = (__bf16)qr[c * 32 + b];
    }

    // ALiBi: cb = slope2*((jt*16+g*4+r) - (qbase+col))
    float cb[2][4];
    #pragma unroll
    for (int jt = 0; jt < 2; ++jt)
        #pragma unroll
        for (int r = 0; r < 4; ++r)
            cb[jt][r] = slope2 * (float)(jt * 16 + g * 4 + r - (qbase + col));

    float m = -1e30f, l = 0.0f;
    f32x4 acc[4];
    #pragma unroll
    for (int dt = 0; dt < 4; ++dt) acc[dt] = (f32x4)0.0f;

    // ---- staging setup ----
    const int hid  = tid & 255;
    const int krow = hid >> 3;
    const int kcol = (hid & 7) * 8;
    const int vc   = hid & 63;
    const int vr   = (hid >> 6) * 8;

    const char* kis = nullptr;
    const char* vis = nullptr;
    const float* ksrc = nullptr;
    const float* vsrc = nullptr;
    char* kdst  = nullptr;
    char* vtdst = nullptr;
    if constexpr (IMG) {
        const size_t base = ((size_t)h * NTILE_TOT + half * NT) * 4096 + hid * 16;
        kis = kimg + base;
        vis = vtimg + base;
        kdst  = kbase + hid * 16;
        vtdst = vtbase + hid * 16;
    } else {
        ksrc  = kh + (size_t)(kstart + krow) * HEAD_DIM + kcol;
        kdst  = kbase + krow * 128 + ((kcol * 2) ^ ((krow & 7) << 4));
        vsrc  = vh + (size_t)(kstart + vr) * HEAD_DIM + vc;
        vtdst = vtbase + (((vc * 64) + (vr * 2)) ^ ((vc & 7) << 4));
    }

    f32x4 kreg, vreg;   // IMG path: raw 16B image chunks
    f32x4 kr0, kr1;     // direct path
    float vv[8];

    // ---- prologue: stage tile 0 ----
    if constexpr (IMG) {
        kreg = *(const f32x4*)(kis);
        vreg = *(const f32x4*)(vis);
        *(f32x4*)(kdst)  = kreg;
        *(f32x4*)(vtdst) = vreg;
    } else {
        kr0 = *(const f32x4*)(ksrc);
        kr1 = *(const f32x4*)(ksrc + 4);
        #pragma unroll
        for (int j = 0; j < 8; ++j) vv[j] = vsrc[(size_t)j * HEAD_DIM];
        bf16x8 kb16, vb16;
        #pragma unroll
        for (int b = 0; b < 4; ++b) { kb16[b] = (__bf16)kr0[b]; kb16[4 + b] = (__bf16)kr1[b]; }
        #pragma unroll
        for (int j = 0; j < 8; ++j) vb16[j] = (__bf16)vv[j];
        *(bf16x8*)(kdst)  = kb16;
        *(bf16x8*)(vtdst) = vb16;
    }
    __syncthreads();

    for (int t = 0; t < NT; ++t) {
        const int kb  = kstart + t * KVBLK;
        const int buf = t & 1;
        const char* kbuf  = kbase + buf * 4096;
        const char* vtbuf = vtbase + buf * 4096;

        // ---- S^T = K Q^T (swapped operands) ----
        f32x4 sacc[2];
        sacc[0] = (f32x4)0.0f;
        sacc[1] = (f32x4)0.0f;
        #pragma unroll
        for (int jt = 0; jt < 2; ++jt) {
            const int row = jt * 16 + col;
            #pragma unroll
            for (int c = 0; c < 2; ++c) {
                bf16x8 kf = *(const bf16x8*)(kbuf + row * 128
                                             + ((c * 64 + g * 16) ^ ((row & 7) << 4)));
                sacc[jt] = __builtin_amdgcn_mfma_f32_16x16x32_bf16(kf, qf[c], sacc[jt], 0, 0, 0);
            }
        }

        // ---- issue next-tile staging loads (hide under softmax+PV) ----
        if (t + 1 < NT) {
            if constexpr (IMG) {
                kreg = *(const f32x4*)(kis + (size_t)(t + 1) * 4096);
                vreg = *(const f32x4*)(vis + (size_t)(t + 1) * 4096);
            } else {
                const float* ks = ksrc + (size_t)(t + 1) * KVBLK * HEAD_DIM;
                const float* vs = vsrc + (size_t)(t + 1) * KVBLK * HEAD_DIM;
                kr0 = *(const f32x4*)(ks);
                kr1 = *(const f32x4*)(ks + 4);
                #pragma unroll
                for (int j = 0; j < 8; ++j) vv[j] = vs[(size_t)j * HEAD_DIM];
            }
        }

        // ---- scale + alibi (base-2); lane holds s[k-local] for its q-row ----
        const float skb = slope2 * (float)kb;
        float s[2][4];
        #pragma unroll
        for (int jt = 0; jt < 2; ++jt)
            #pragma unroll
            for (int r = 0; r < 4; ++r)
                s[jt][r] = sacc[jt][r] * scale2 + (cb[jt][r] + skb);

        // ---- online softmax: scalar per lane, 2+2 shfl across g-groups ----
        float x = s[0][0];
        #pragma unroll
        for (int jt = 0; jt < 2; ++jt)
            #pragma unroll
            for (int r = 0; r < 4; ++r) x = fmaxf(x, s[jt][r]);
        x = fmaxf(x, __shfl_xor(x, 16));
        x = fmaxf(x, __shfl_xor(x, 32));
        float mn    = fmaxf(m, x);
        float alpha = __builtin_amdgcn_exp2f(m - mn);
        m = mn;
        float p[2][4], y = 0.0f;
        #pragma unroll
        for (int jt = 0; jt < 2; ++jt)
            #pragma unroll
            for (int r = 0; r < 4; ++r) {
                p[jt][r] = __builtin_amdgcn_exp2f(s[jt][r] - mn);
                y += p[jt][r];
            }
        y += __shfl_xor(y, 16);
        y += __shfl_xor(y, 32);
        l = l * alpha + y;
        #pragma unroll
        for (int dt = 0; dt < 4; ++dt) acc[dt] *= alpha;

#if HAVE_MFMA16
        // ---- ZERO-SHUFFLE PV: two K=16 MFMAs per dt; B = own p[jt][*] ----
        bf16x4 pf0, pf1;
        #pragma unroll
        for (int b = 0; b < 4; ++b) { pf0[b] = (__bf16)p[0][b]; pf1[b] = (__bf16)p[1][b]; }
        const s16x4 pb0 = __builtin_bit_cast(s16x4, pf0);
        const s16x4 pb1 = __builtin_bit_cast(s16x4, pf1);
        #pragma unroll
        for (int dt = 0; dt < 4; ++dt) {
            const int vrow = dt * 16 + col;
            const int rb   = vrow * 64;
            const int swz  = (vrow & 7) << 4;
            bf16x4 vf0 = *(const bf16x4*)(vtbuf + ((rb + g * 8) ^ swz));
            bf16x4 vf1 = *(const bf16x4*)(vtbuf + ((rb + 32 + g * 8) ^ swz));
            acc[dt] = __builtin_amdgcn_mfma_f32_16x16x16bf16_1k(
                __builtin_bit_cast(s16x4, vf0), pb0, acc[dt], 0, 0, 0);
            acc[dt] = __builtin_amdgcn_mfma_f32_16x16x16bf16_1k(
                __builtin_bit_cast(s16x4, vf1), pb1, acc[dt], 0, 0, 0);
        }
#else
        // ---- fallback: pack + 8-shfl permute + K=32 PV ----
        unsigned pk00 = pkbf(p[0][0], p[0][1]);
        unsigned pk01 = pkbf(p[0][2], p[0][3]);
        unsigned pk10 = pkbf(p[1][0], p[1][1]);
        unsigned pk11 = pkbf(p[1][2], p[1][3]);
        const int srcA = col + ((g & 1) << 5);
        const int srcB = srcA + 16;
        unsigned a00 = __shfl(pk00, srcA), a01 = __shfl(pk01, srcA);
        unsigned a10 = __shfl(pk10, srcA), a11 = __shfl(pk11, srcA);
        unsigned b00 = __shfl(pk00, srcB), b01 = __shfl(pk01, srcB);
        unsigned b10 = __shfl(pk10, srcB), b11 = __shfl(pk11, srcB);
        const bool hi = g >= 2;
        u32x4 pu;
        pu[0] = hi ? a10 : a00;
        pu[1] = hi ? a11 : a01;
        pu[2] = hi ? b10 : b00;
        pu[3] = hi ? b11 : b01;
        bf16x8 pf = __builtin_bit_cast(bf16x8, pu);
        #pragma unroll
        for (int dt = 0; dt < 4; ++dt) {
            const int vrow = dt * 16 + col;
            bf16x8 vf = *(const bf16x8*)(vtbuf
                            + ((vrow * 64 + g * 16) ^ ((vrow & 7) << 4)));
            acc[dt] = __builtin_amdgcn_mfma_f32_16x16x32_bf16(vf, pf, acc[dt], 0, 0, 0);
        }
#endif

        // ---- write next tile into the other LDS buffer ----
        if (t + 1 < NT) {
            const int nb = (t + 1) & 1;
            if constexpr (IMG) {
                *(f32x4*)(kdst  + nb * 4096) = kreg;
                *(f32x4*)(vtdst + nb * 4096) = vreg;
            } else {
                bf16x8 kb16, vb16;
                #pragma unroll
                for (int b = 0; b < 4; ++b) { kb16[b] = (__bf16)kr0[b]; kb16[4 + b] = (__bf16)kr1[b]; }
                #pragma unroll
                for (int j = 0; j < 8; ++j) vb16[j] = (__bf16)vv[j];
                *(bf16x8*)(kdst  + nb * 4096) = kb16;
                *(bf16x8*)(vtdst + nb * 4096) = vb16;
            }
        }
        __syncthreads();
    }

    // ---- merge halves (flash combine in O^T layout, base-2 domain) ----
    float* eacc = (float*)smem;            // [w4][q=col 16][d 64]
    float* eml  = (float*)(smem + 16384);  // [w4*16+col]*2

    if (half == 1) {
        #pragma unroll
        for (int dt = 0; dt < 4; ++dt)
            *(f32x4*)(eacc + w4 * 1024 + col * 64 + dt * 16 + g * 4) = acc[dt];
        if (g == 0) {
            eml[(w4 * 16 + col) * 2 + 0] = m;
            eml[(w4 * 16 + col) * 2 + 1] = l;
        }
    }
    __syncthreads();
    if (half == 0) {
        float m2 = eml[(w4 * 16 + col) * 2 + 0];
        float l2 = eml[(w4 * 16 + col) * 2 + 1];
        float mm = fmaxf(m, m2);
        float a1 = __builtin_amdgcn_exp2f(m - mm);
        float a2 = __builtin_amdgcn_exp2f(m2 - mm);
        float inv = 1.0f / (l * a1 + l2 * a2);
        float* orow = out + ((size_t)h * SEQ_LEN + qbase + col) * HEAD_DIM;
        #pragma unroll
        for (int dt = 0; dt < 4; ++dt) {
            f32x4 o2 = *(const f32x4*)(eacc + w4 * 1024 + col * 64 + dt * 16 + g * 4);
            *(f32x4*)(orow + dt * 16 + g * 4) = (acc[dt] * a1 + o2 * a2) * inv;
        }
    }
}

extern "C" void kernel_launch(void* const* d_in, const int* in_sizes, int n_in,
                              void* d_out, int out_size, void* d_ws, size_t ws_size,
                              hipStream_t stream) {
    const float* q = (const float*)d_in[0];
    const float* k = (const float*)d_in[1];
    const float* v = (const float*)d_in[2];
    float* out = (float*)d_out;

    const size_t imgBytes = (size_t)N_HEADS * NTILE_TOT * 4096;   // 4 MiB each

    dim3 grid(SEQ_LEN / 64, N_HEADS, 1);
    if (ws_size >= 2 * imgBytes) {
        char* kimg  = (char*)d_ws;
        char* vtimg = kimg + imgBytes;
        prep_kernel<<<dim3(NTILE_TOT, N_HEADS, 1), dim3(256, 1, 1), 0, stream>>>(
            k, v, kimg, vtimg);
        attn_alibi_kernel<true><<<grid, dim3(512, 1, 1), 0, stream>>>(
            q, k, v, out, kimg, vtimg);
    } else {
        attn_alibi_kernel<false><<<grid, dim3(512, 1, 1), 0, stream>>>(
            q, k, v, out, nullptr, nullptr);
    }
}

// Round 11
// 48.951 us; speedup vs baseline: 2.8186x; 1.0506x over previous
//
#include <hip/hip_runtime.h>
#include <hip/hip_bf16.h>
#include <stdint.h>

#define N_HEADS 16
#define HEAD_DIM 64
#define SEQ_LEN 2048
#define KVBLK 64                    // two verified 32-row sub-blocks per iter
#define NT 16                       // iterations per half-stream
#define NTILE_TOT (SEQ_LEN / 32)    // 32-row image tiles

typedef __bf16 bf16x8 __attribute__((ext_vector_type(8)));
typedef __bf16 bf16x4 __attribute__((ext_vector_type(4)));
typedef short  s16x4  __attribute__((ext_vector_type(4)));
typedef float  f32x4  __attribute__((ext_vector_type(4)));
typedef unsigned int u32x4 __attribute__((ext_vector_type(4)));

#if __has_builtin(__builtin_amdgcn_mfma_f32_16x16x16bf16_1k)
#define HAVE_MFMA16 1
#else
#define HAVE_MFMA16 0
#endif

static __device__ __forceinline__ unsigned pkbf(float a, float b) {
    union { __bf16 h[2]; unsigned u; } t;
    t.h[0] = (__bf16)a; t.h[1] = (__bf16)b;
    return t.u;
}

// Prep: swizzled bf16 images of K (row-major) and Vt (transposed), one 4 KB
// block per (head, 32-row tile) — byte-exact replicas of the verified LDS
// tiles (identical write formulas, executed once instead of 32x/head).
//   K : row-major bf16 [32][64], addr = row*128 + (off ^ ((row&7)<<4))
//   Vt: transposed bf16, FULL-ADDRESS XOR: addr = (vc*64 + off) ^ ((vc&7)<<4)
__global__ __launch_bounds__(256)
void prep_kernel(const float* __restrict__ k,
                 const float* __restrict__ v,
                 char* __restrict__ kimg,
                 char* __restrict__ vtimg) {
    const int ts  = blockIdx.x;         // 32-row tile 0..63
    const int h   = blockIdx.y;
    const int tid = threadIdx.x;
    const int s0  = ts * 32;
    const size_t blk = ((size_t)h * NTILE_TOT + ts) * 4096;

    const int krow = tid >> 3;
    const int kcol = (tid & 7) * 8;
    const float* ks = k + ((size_t)h * SEQ_LEN + s0 + krow) * HEAD_DIM + kcol;
    f32x4 a = *(const f32x4*)ks;
    f32x4 b = *(const f32x4*)(ks + 4);
    bf16x8 kb;
    #pragma unroll
    for (int i = 0; i < 4; ++i) { kb[i] = (__bf16)a[i]; kb[4 + i] = (__bf16)b[i]; }
    *(bf16x8*)(kimg + blk + krow * 128 + ((kcol * 2) ^ ((krow & 7) << 4))) = kb;

    const int vc = tid & 63;
    const int vr = (tid >> 6) * 8;
    const float* vs = v + ((size_t)h * SEQ_LEN + s0 + vr) * HEAD_DIM + vc;
    bf16x8 vb;
    #pragma unroll
    for (int j = 0; j < 8; ++j) vb[j] = (__bf16)vs[(size_t)j * HEAD_DIM];
    *(bf16x8*)(vtimg + blk + (((vc * 64) + (vr * 2)) ^ ((vc & 7) << 4))) = vb;
}

// 8-wave WG, 2-way intra-WG KV split; KVBLK=64 (2 sub-blocks of the verified
// 32-row layout per iteration): halves barriers + softmax/rescale per kv.
// Defer-rescale (T13, THR=8 base-2): skip alpha path when tile max doesn't
// grow - exact when skipped, p <= 2^8 safe in bf16.
// IMG staging = verbatim 16B/thread copies of prebuilt image blocks.
// LDS (65536 B): [0,32K) K [half][dbuf][2 sub][4096], [32K,64K) Vt same.
template <bool IMG>
__global__ __launch_bounds__(512, 2)
void attn_alibi_kernel(const float* __restrict__ q,
                       const float* __restrict__ k,
                       const float* __restrict__ v,
                       float* __restrict__ out,
                       const char* __restrict__ kimg,
                       const char* __restrict__ vtimg) {
    const int tid  = threadIdx.x;
    const int wave = tid >> 6;
    const int lane = tid & 63;
    const int col  = lane & 15;
    const int g    = lane >> 4;
    const int half = wave >> 2;
    const int w4   = wave & 3;

    const int h      = blockIdx.y;
    const int qbase  = blockIdx.x * 64 + w4 * 16;
    const int kstart = half * (NT * KVBLK);

    const float* qh = q + (size_t)h * SEQ_LEN * HEAD_DIM;
    const float* kh = k + (size_t)h * SEQ_LEN * HEAD_DIM;
    const float* vh = v + (size_t)h * SEQ_LEN * HEAD_DIM;

    __shared__ alignas(16) char smem[65536];
    char* kbase  = smem + half * 16384;
    char* vtbase = smem + 32768 + half * 16384;

    const float LOG2E  = 1.4426950408889634f;
    const float scale2 = 0.125f * LOG2E;
    const float slope  = exp2f(-0.5f * (float)(h + 1));
    const float slope2 = slope * LOG2E;

    // ---- Q B-fragments: lane holds Q[qbase+col][c*32 + g*8 + b] ----
    bf16x8 qf[2];
    {
        const float* qr = qh + (size_t)(qbase + col) * HEAD_DIM + g * 8;
        #pragma unroll
        for (int c = 0; c < 2; ++c)
            #pragma unroll
            for (int b = 0; b < 8; ++b) qf[c][b] = (__bf16)qr[c * 32 + b];
    }

    // ALiBi: cb[i] covers k-local i*16+g*4+r, i=0..3 over the 64-row tile
    float cb[4][4];
    #pragma unroll
    for (int i = 0; i < 4; ++i)
        #pragma unroll
        for (int r = 0; r < 4; ++r)
            cb[i][r] = slope2 * (float)(i * 16 + g * 4 + r - (qbase + col));

    float m = -1e30f, l = 0.0f;
    f32x4 acc[4];
    #pragma unroll
    for (int dt = 0; dt < 4; ++dt) acc[dt] = (f32x4)0.0f;

    // ---- staging setup (256 threads per half) ----
    const int hid  = tid & 255;
    const int krow = hid >> 3;
    const int kcol = (hid & 7) * 8;
    const int vc   = hid & 63;
    const int vr   = (hid >> 6) * 8;

    const char* kis = nullptr; const char* vis = nullptr;
    const float* ksrc = nullptr; const float* vsrc = nullptr;
    char* kdst = nullptr; char* vtdst = nullptr;
    if constexpr (IMG) {
        const size_t base = ((size_t)h * NTILE_TOT + half * (NTILE_TOT / 2)) * 4096
                          + hid * 16;
        kis = kimg + base;  vis = vtimg + base;
        kdst  = kbase + hid * 16;
        vtdst = vtbase + hid * 16;
    } else {
        ksrc  = kh + (size_t)(kstart + krow) * HEAD_DIM + kcol;
        kdst  = kbase + krow * 128 + ((kcol * 2) ^ ((krow & 7) << 4));
        vsrc  = vh + (size_t)(kstart + vr) * HEAD_DIM + vc;
        vtdst = vtbase + (((vc * 64) + (vr * 2)) ^ ((vc & 7) << 4));
    }

    f32x4 kreg[2], vreg[2];          // IMG: raw 16B chunks, one per sub-block
    f32x4 kr[2][2];                  // direct path
    float vv[2][8];

    // ---- prologue: stage iteration 0 (both sub-blocks) into buf 0 ----
    if constexpr (IMG) {
        #pragma unroll
        for (int sb = 0; sb < 2; ++sb) {
            kreg[sb] = *(const f32x4*)(kis + sb * 4096);
            vreg[sb] = *(const f32x4*)(vis + sb * 4096);
            *(f32x4*)(kdst  + sb * 4096) = kreg[sb];
            *(f32x4*)(vtdst + sb * 4096) = vreg[sb];
        }
    } else {
        #pragma unroll
        for (int sb = 0; sb < 2; ++sb) {
            const float* ks = ksrc + (size_t)(sb * 32) * HEAD_DIM;
            const float* vs = vsrc + (size_t)(sb * 32) * HEAD_DIM;
            kr[sb][0] = *(const f32x4*)(ks);
            kr[sb][1] = *(const f32x4*)(ks + 4);
            #pragma unroll
            for (int j = 0; j < 8; ++j) vv[sb][j] = vs[(size_t)j * HEAD_DIM];
            bf16x8 kb16, vb16;
            #pragma unroll
            for (int b = 0; b < 4; ++b) { kb16[b] = (__bf16)kr[sb][0][b]; kb16[4 + b] = (__bf16)kr[sb][1][b]; }
            #pragma unroll
            for (int j = 0; j < 8; ++j) vb16[j] = (__bf16)vv[sb][j];
            *(bf16x8*)(kdst  + sb * 4096) = kb16;
            *(bf16x8*)(vtdst + sb * 4096) = vb16;
        }
    }
    __syncthreads();

    for (int t = 0; t < NT; ++t) {
        const int kb  = kstart + t * KVBLK;
        const int buf = t & 1;
        const char* kbuf  = kbase + buf * 8192;
        const char* vtbuf = vtbase + buf * 8192;

        // ---- S^T = K Q^T over 64 k-rows (2 sub-blocks x 2 jt) ----
        f32x4 sacc[4];
        #pragma unroll
        for (int i = 0; i < 4; ++i) sacc[i] = (f32x4)0.0f;
        #pragma unroll
        for (int sb = 0; sb < 2; ++sb) {
            #pragma unroll
            for (int jt = 0; jt < 2; ++jt) {
                const int row = jt * 16 + col;
                const int i   = sb * 2 + jt;
                #pragma unroll
                for (int c = 0; c < 2; ++c) {
                    bf16x8 kf = *(const bf16x8*)(kbuf + sb * 4096 + row * 128
                                                 + ((c * 64 + g * 16) ^ ((row & 7) << 4)));
                    sacc[i] = __builtin_amdgcn_mfma_f32_16x16x32_bf16(kf, qf[c], sacc[i], 0, 0, 0);
                }
            }
        }

        // ---- issue next-iteration staging loads ----
        if (t + 1 < NT) {
            if constexpr (IMG) {
                #pragma unroll
                for (int sb = 0; sb < 2; ++sb) {
                    kreg[sb] = *(const f32x4*)(kis + (size_t)((t + 1) * 2 + sb) * 4096);
                    vreg[sb] = *(const f32x4*)(vis + (size_t)((t + 1) * 2 + sb) * 4096);
                }
            } else {
                #pragma unroll
                for (int sb = 0; sb < 2; ++sb) {
                    const float* ks = ksrc + (size_t)((t + 1) * 64 + sb * 32) * HEAD_DIM;
                    const float* vs = vsrc + (size_t)((t + 1) * 64 + sb * 32) * HEAD_DIM;
                    kr[sb][0] = *(const f32x4*)(ks);
                    kr[sb][1] = *(const f32x4*)(ks + 4);
                    #pragma unroll
                    for (int j = 0; j < 8; ++j) vv[sb][j] = vs[(size_t)j * HEAD_DIM];
                }
            }
        }

        // ---- scale + alibi (base-2) ----
        const float skb = slope2 * (float)kb;
        float s[4][4];
        #pragma unroll
        for (int i = 0; i < 4; ++i)
            #pragma unroll
            for (int r = 0; r < 4; ++r)
                s[i][r] = sacc[i][r] * scale2 + (cb[i][r] + skb);

        // ---- tile max over 64 kv (tree + 2 shfl across g-groups) ----
        float x01a = fmaxf(s[0][0], s[0][1]), x01b = fmaxf(s[0][2], s[0][3]);
        float x23a = fmaxf(s[1][0], s[1][1]), x23b = fmaxf(s[1][2], s[1][3]);
        float x45a = fmaxf(s[2][0], s[2][1]), x45b = fmaxf(s[2][2], s[2][3]);
        float x67a = fmaxf(s[3][0], s[3][1]), x67b = fmaxf(s[3][2], s[3][3]);
        float x = fmaxf(fmaxf(fmaxf(x01a, x01b), fmaxf(x23a, x23b)),
                        fmaxf(fmaxf(x45a, x45b), fmaxf(x67a, x67b)));
        x = fmaxf(x, __shfl_xor(x, 16));
        x = fmaxf(x, __shfl_xor(x, 32));

        // ---- defer-rescale: only pay alpha path when max grew > 8 ----
        if (__any(x - m > 8.0f)) {
            float mn    = fmaxf(m, x);
            float alpha = __builtin_amdgcn_exp2f(m - mn);
            m = mn;
            l *= alpha;
            #pragma unroll
            for (int dt = 0; dt < 4; ++dt) acc[dt] *= alpha;
        }

        // ---- p = exp2(s - m), row sum ----
        float p[4][4], y = 0.0f;
        #pragma unroll
        for (int i = 0; i < 4; ++i)
            #pragma unroll
            for (int r = 0; r < 4; ++r) {
                p[i][r] = __builtin_amdgcn_exp2f(s[i][r] - m);
                y += p[i][r];
            }
        y += __shfl_xor(y, 16);
        y += __shfl_xor(y, 32);
        l += y;

#if HAVE_MFMA16
        // ---- ZERO-SHUFFLE PV: K=16 MFMAs, B = own p[i][0..3] ----
        s16x4 pb[4];
        #pragma unroll
        for (int i = 0; i < 4; ++i) {
            bf16x4 pf;
            #pragma unroll
            for (int b = 0; b < 4; ++b) pf[b] = (__bf16)p[i][b];
            pb[i] = __builtin_bit_cast(s16x4, pf);
        }
        #pragma unroll
        for (int dt = 0; dt < 4; ++dt) {
            const int vrow = dt * 16 + col;
            const int rb   = vrow * 64;
            const int swz  = (vrow & 7) << 4;
            #pragma unroll
            for (int i = 0; i < 4; ++i) {
                const int sb = i >> 1, jt = i & 1;
                bf16x4 vf = *(const bf16x4*)(vtbuf + sb * 4096
                                             + ((rb + jt * 32 + g * 8) ^ swz));
                acc[dt] = __builtin_amdgcn_mfma_f32_16x16x16bf16_1k(
                    __builtin_bit_cast(s16x4, vf), pb[i], acc[dt], 0, 0, 0);
            }
        }
#else
        // ---- fallback: per sub-block pack + 8-shfl permute + K=32 PV ----
        #pragma unroll
        for (int sb = 0; sb < 2; ++sb) {
            unsigned pk00 = pkbf(p[sb * 2][0],     p[sb * 2][1]);
            unsigned pk01 = pkbf(p[sb * 2][2],     p[sb * 2][3]);
            unsigned pk10 = pkbf(p[sb * 2 + 1][0], p[sb * 2 + 1][1]);
            unsigned pk11 = pkbf(p[sb * 2 + 1][2], p[sb * 2 + 1][3]);
            const int srcA = col + ((g & 1) << 5);
            const int srcB = srcA + 16;
            unsigned a00 = __shfl(pk00, srcA), a01 = __shfl(pk01, srcA);
            unsigned a10 = __shfl(pk10, srcA), a11 = __shfl(pk11, srcA);
            unsigned b00 = __shfl(pk00, srcB), b01 = __shfl(pk01, srcB);
            unsigned b10 = __shfl(pk10, srcB), b11 = __shfl(pk11, srcB);
            const bool hi = g >= 2;
            u32x4 pu;
            pu[0] = hi ? a10 : a00;
            pu[1] = hi ? a11 : a01;
            pu[2] = hi ? b10 : b00;
            pu[3] = hi ? b11 : b01;
            bf16x8 pf = __builtin_bit_cast(bf16x8, pu);
            #pragma unroll
            for (int dt = 0; dt < 4; ++dt) {
                const int vrow = dt * 16 + col;
                bf16x8 vf = *(const bf16x8*)(vtbuf + sb * 4096
                                + ((vrow * 64 + g * 16) ^ ((vrow & 7) << 4)));
                acc[dt] = __builtin_amdgcn_mfma_f32_16x16x32_bf16(vf, pf, acc[dt], 0, 0, 0);
            }
        }
#endif

        // ---- write next iteration into the other LDS buffer ----
        if (t + 1 < NT) {
            const int nb = (t + 1) & 1;
            if constexpr (IMG) {
                #pragma unroll
                for (int sb = 0; sb < 2; ++sb) {
                    *(f32x4*)(kdst  + nb * 8192 + sb * 4096) = kreg[sb];
                    *(f32x4*)(vtdst + nb * 8192 + sb * 4096) = vreg[sb];
                }
            } else {
                #pragma unroll
                for (int sb = 0; sb < 2; ++sb) {
                    bf16x8 kb16, vb16;
                    #pragma unroll
                    for (int b = 0; b < 4; ++b) { kb16[b] = (__bf16)kr[sb][0][b]; kb16[4 + b] = (__bf16)kr[sb][1][b]; }
                    #pragma unroll
                    for (int j = 0; j < 8; ++j) vb16[j] = (__bf16)vv[sb][j];
                    *(bf16x8*)(kdst  + nb * 8192 + sb * 4096) = kb16;
                    *(bf16x8*)(vtdst + nb * 8192 + sb * 4096) = vb16;
                }
            }
        }
        __syncthreads();
    }

    // ---- merge halves (flash combine in O^T layout, base-2 domain) ----
    float* eacc = (float*)smem;            // [w4][q=col 16][d 64]
    float* eml  = (float*)(smem + 16384);  // [w4*16+col]*2

    if (half == 1) {
        #pragma unroll
        for (int dt = 0; dt < 4; ++dt)
            *(f32x4*)(eacc + w4 * 1024 + col * 64 + dt * 16 + g * 4) = acc[dt];
        if (g == 0) {
            eml[(w4 * 16 + col) * 2 + 0] = m;
            eml[(w4 * 16 + col) * 2 + 1] = l;
        }
    }
    __syncthreads();
    if (half == 0) {
        float m2 = eml[(w4 * 16 + col) * 2 + 0];
        float l2 = eml[(w4 * 16 + col) * 2 + 1];
        float mm = fmaxf(m, m2);
        float a1 = __builtin_amdgcn_exp2f(m - mm);
        float a2 = __builtin_amdgcn_exp2f(m2 - mm);
        float inv = 1.0f / (l * a1 + l2 * a2);
        float* orow = out + ((size_t)h * SEQ_LEN + qbase + col) * HEAD_DIM;
        #pragma unroll
        for (int dt = 0; dt < 4; ++dt) {
            f32x4 o2 = *(const f32x4*)(eacc + w4 * 1024 + col * 64 + dt * 16 + g * 4);
            *(f32x4*)(orow + dt * 16 + g * 4) = (acc[dt] * a1 + o2 * a2) * inv;
        }
    }
}

extern "C" void kernel_launch(void* const* d_in, const int* in_sizes, int n_in,
                              void* d_out, int out_size, void* d_ws, size_t ws_size,
                              hipStream_t stream) {
    const float* q = (const float*)d_in[0];
    const float* k = (const float*)d_in[1];
    const float* v = (const float*)d_in[2];
    float* out = (float*)d_out;

    const size_t imgBytes = (size_t)N_HEADS * NTILE_TOT * 4096;   // 4 MiB each

    dim3 grid(SEQ_LEN / 64, N_HEADS, 1);
    if (ws_size >= 2 * imgBytes) {
        char* kimg  = (char*)d_ws;
        char* vtimg = kimg + imgBytes;
        prep_kernel<<<dim3(NTILE_TOT, N_HEADS, 1), dim3(256, 1, 1), 0, stream>>>(
            k, v, kimg, vtimg);
        attn_alibi_kernel<true><<<grid, dim3(512, 1, 1), 0, stream>>>(
            q, k, v, out, kimg, vtimg);
    } else {
        attn_alibi_kernel<false><<<grid, dim3(512, 1, 1), 0, stream>>>(
            q, k, v, out, nullptr, nullptr);
    }
}